// Round 9
// baseline (512.565 us; speedup 1.0000x reference)
//
#include <hip/hip_runtime.h>
#include <stdint.h>

// ---- problem constants ----
#define HEADS 8
#define KSZ   4
#define STRD  2
#define BB    8
#define LL    2048
#define CC    1024
#define N3    3072
#define NW    1023            // windows
#define M1    (BB*LL)         // 16384 rows of qkv GEMM (and of z GEMM)
#define GK    1024            // K of both GEMMs
#define NTT   16              // K-tiles per output tile (GK/64)

typedef __bf16 bf16;
typedef __bf16 bf16x8 __attribute__((ext_vector_type(8)));
typedef float  f32x4  __attribute__((ext_vector_type(4)));
typedef unsigned int  u32;
typedef unsigned short u16;

__device__ __forceinline__ float bflo(u32 u) { return __uint_as_float(u << 16); }
__device__ __forceinline__ float bfhi(u32 u) { return __uint_as_float(u & 0xffff0000u); }
__device__ __forceinline__ u16 f2bf(float f) { bf16 b = (bf16)f; return __builtin_bit_cast(u16, b); }

#define AS3(p) ((__attribute__((address_space(3))) void*)(p))
#define AS1(p) ((const __attribute__((address_space(1))) void*)(p))

// ---------------- cast x (f32 -> bf16), vectorized ----------------
__global__ __launch_bounds__(256) void cast_x_k(const float* __restrict__ in,
                                                bf16* __restrict__ out, int n4)
{
    int i = blockIdx.x * 256 + threadIdx.x;
    int stride = gridDim.x * 256;
    for (; i < n4; i += stride) {
        float4 f = reinterpret_cast<const float4*>(in)[i];
        ushort4 u;
        u.x = f2bf(f.x); u.y = f2bf(f.y); u.z = f2bf(f.z); u.w = f2bf(f.w);
        reinterpret_cast<ushort4*>(out)[i] = u;
    }
}

// ---------------- transpose + cast: src f32 [R][Ccol] -> dst bf16 [Ccol][R] ----------------
__global__ __launch_bounds__(256) void transpose_cast_k(const float* __restrict__ src,
                                                        bf16* __restrict__ dst,
                                                        int R, int Ccol)
{
    __shared__ float t[32][33];
    int tx = threadIdx.x & 31, ty = threadIdx.x >> 5;   // 32 x 8
    int c0 = blockIdx.x * 32, r0 = blockIdx.y * 32;
#pragma unroll
    for (int yy = 0; yy < 32; yy += 8)
        t[ty + yy][tx] = src[(size_t)(r0 + ty + yy) * Ccol + c0 + tx];
    __syncthreads();
#pragma unroll
    for (int yy = 0; yy < 32; yy += 8)
        dst[(size_t)(c0 + ty + yy) * R + r0 + tx] = (bf16)t[tx][ty + yy];
}

// ---------------- persistent 256x256 bf16 GEMM, 4-phase + 1-phase read-ahead ----
// Ledger (verified r4-r8 base + read-ahead): stage A(j+2)@P3, B(j+2)@P4 into
// buf[j&1]. vmcnt(4)@P3-end ensures A(j+1),B(j+1) landed BEFORE P3's barrier
// (in-order vmcnt: oldest 8 of {A(j+1),B(j+1),A(j+2)} drained) -> P4 may read
// next-tile fragments from buf[(j+1)&1]. Ring Q1(aLo,bLo) Q2(aLo,bHi)
// Q3(aHi,bHi) Q4(aHi,bLo); aHi/bHi read at P1 (drained by P2-start lgkm0,
// before the P2 barrier that gates P3's A-overwrite and P4's B-overwrite).
// Next aLo',bLo' read at P4, drained at next P1-start lgkm0.
__device__ __forceinline__ void stage8(const bf16* __restrict__ G, bf16* dst,
                                       int baserow, int kt,
                                       int wid, int l, int kch)
{
#pragma unroll
    for (int qd = 0; qd < 4; ++qd) {
        int row = ((wid * 4 + qd) << 3) + (l >> 3);
        const bf16* src = G + (size_t)(baserow + row) * GK + kt * 64 + kch;
        __builtin_amdgcn_global_load_lds(AS1(src), AS3(dst + (wid * 4 + qd) * 512), 16, 0, 0);
    }
}

#define LGKM0 { asm volatile("s_waitcnt lgkmcnt(0)" ::: "memory"); __builtin_amdgcn_sched_barrier(0); }
#define BARR  { __builtin_amdgcn_s_barrier(); __builtin_amdgcn_sched_barrier(0); }
#define MFMAQ(AF, BF, MI, NI)                                                          \
    __builtin_amdgcn_s_setprio(1);                                                     \
    _Pragma("unroll") for (int m = 0; m < 4; ++m)                                      \
      _Pragma("unroll") for (int n = 0; n < 2; ++n)                                    \
        _Pragma("unroll") for (int ks = 0; ks < 2; ++ks)                               \
            acc[MI + m][NI + n] = __builtin_amdgcn_mfma_f32_16x16x32_bf16(             \
                AF[m][ks], BF[n][ks], acc[MI + m][NI + n], 0, 0, 0);                   \
    __builtin_amdgcn_s_setprio(0);

#define SLOT(CB, NB, CFA, CFB, NFA, NFB, J)                                            \
{                                                                                      \
    const int j_ = (J);                                                                \
    const int jn_ = j_ + 2;                                                            \
    int m0n_ = 0, n0n_ = 0;                                                            \
    if (jn_ < JT) {                                                                    \
        int tin_ = wg * T + (jn_ >> 4);                                                \
        m0n_ = (tin_ / NBN) << 8; n0n_ = (tin_ % NBN) << 8;                            \
    }                                                                                  \
    /* P1: drain P4-issued reads; issue aHi,bHi; MFMA Q1 */                            \
    LGKM0                                                                              \
    _Pragma("unroll") for (int m = 0; m < 4; ++m)                                      \
        _Pragma("unroll") for (int ks = 0; ks < 2; ++ks)                               \
            aHi[m][ks] = *(const bf16x8*)(&sA[CB][(rA + 64 + m * 16) * 64 + offK[ks]]);\
    _Pragma("unroll") for (int n = 0; n < 2; ++n)                                      \
        _Pragma("unroll") for (int ks = 0; ks < 2; ++ks)                               \
            bHi[n][ks] = *(const bf16x8*)(&sB[CB][(rB + 32 + n * 16) * 64 + offK[ks]]);\
    MFMAQ(CFA, CFB, 0, 0)                                                              \
    BARR                                                                               \
    /* P2: drain aHi,bHi (gate before A/B overwrite); MFMA Q2 */                       \
    LGKM0                                                                              \
    MFMAQ(CFA, bHi, 0, 2)                                                              \
    BARR                                                                               \
    /* P3: stage A(j+2); MFMA Q3; vmcnt(4|0); barrier */                               \
    if (jn_ < JT) stage8(A, sA[CB], m0n_, jn_ & (NTT - 1), wid, l, kch);               \
    MFMAQ(aHi, bHi, 4, 2)                                                              \
    if (j_ < JT - 2)       asm volatile("s_waitcnt vmcnt(4)" ::: "memory");            \
    else if (j_ == JT - 2) asm volatile("s_waitcnt vmcnt(0)" ::: "memory");            \
    BARR                                                                               \
    /* P4: read next-tile aLo',bLo' from buf NB; stage B(j+2); MFMA Q4 */              \
    if (j_ + 1 < JT) {                                                                 \
        _Pragma("unroll") for (int m = 0; m < 4; ++m)                                  \
            _Pragma("unroll") for (int ks = 0; ks < 2; ++ks)                           \
                NFA[m][ks] = *(const bf16x8*)(&sA[NB][(rA + m * 16) * 64 + offK[ks]]); \
        _Pragma("unroll") for (int n = 0; n < 2; ++n)                                  \
            _Pragma("unroll") for (int ks = 0; ks < 2; ++ks)                           \
                NFB[n][ks] = *(const bf16x8*)(&sB[NB][(rB + n * 16) * 64 + offK[ks]]); \
    }                                                                                  \
    if (jn_ < JT) stage8(Bt, sB[CB], n0n_, jn_ & (NTT - 1), wid, l, kch);              \
    MFMAQ(aHi, CFB, 4, 0)                                                              \
    BARR                                                                               \
}

template <int OUT_MODE, int T, int NBN>
__global__ __launch_bounds__(512, 1) void gemm8p_k(const bf16* __restrict__ A,
                                                   const bf16* __restrict__ Bt,
                                                   void* __restrict__ Cout,
                                                   const float* __restrict__ bias)
{
    __shared__ __attribute__((aligned(16))) bf16 sA[2][256 * 64];
    __shared__ __attribute__((aligned(16))) bf16 sB[2][256 * 64];
    const int Nn = NBN << 8;

    const int tid = threadIdx.x;
    const int l = tid & 63, wid = tid >> 6;
    const int wm = wid >> 2, wn = wid & 3;
    const int l15 = l & 15, l4 = l >> 4;
    const int xr = (l & 7) << 4;                      // read-side byte XOR (row&7 == l&7)
    const int kch = ((l & 7) ^ ((l >> 3) & 7)) * 8;   // write-side inverse-swizzled k offset

    // XCD-aware block swizzle (grid = 256, % 8 == 0, bijective)
    const int nwg = gridDim.x;
    const int wg = ((blockIdx.x & 7) * (nwg >> 3)) + (blockIdx.x >> 3);
    const int JT = T * NTT;

    int ti = wg * T;                                  // current output tile
    int m0 = (ti / NBN) << 8, n0 = (ti % NBN) << 8;

    const int rA = wm * 128 + l15;
    const int rB = wn * 64 + l15;
    int offK[2];
#pragma unroll
    for (int ks = 0; ks < 2; ++ks)
        offK[ks] = ((ks * 64 + l4 * 16) ^ xr) >> 1;

    f32x4 acc[8][4] = {};
    bf16x8 aLo0[4][2], bLo0[2][2], aLo1[4][2], bLo1[2][2], aHi[4][2], bHi[2][2];

    // prologue: K-tile 0 -> buf0, K-tile 1 -> buf1 (tile ti); then aLo0,bLo0
    stage8(A, sA[0], m0, 0, wid, l, kch);
    stage8(Bt, sB[0], n0, 0, wid, l, kch);
    stage8(A, sA[1], m0, 1, wid, l, kch);
    stage8(Bt, sB[1], n0, 1, wid, l, kch);
    asm volatile("s_waitcnt vmcnt(8)" ::: "memory");   // K-tile 0 landed (own)
    __builtin_amdgcn_s_barrier();                      // -> all waves' tile-0 landed
    __builtin_amdgcn_sched_barrier(0);
#pragma unroll
    for (int m = 0; m < 4; ++m)
#pragma unroll
        for (int ks = 0; ks < 2; ++ks)
            aLo0[m][ks] = *(const bf16x8*)(&sA[0][(rA + m * 16) * 64 + offK[ks]]);
#pragma unroll
    for (int n = 0; n < 2; ++n)
#pragma unroll
        for (int ks = 0; ks < 2; ++ks)
            bLo0[n][ks] = *(const bf16x8*)(&sB[0][(rB + n * 16) * 64 + offK[ks]]);

    for (int jj = 0; jj < JT; jj += 2) {
        SLOT(0, 1, aLo0, bLo0, aLo1, bLo1, jj)
        SLOT(1, 0, aLo1, bLo1, aLo0, bLo0, jj + 1)

        // ---- output-tile boundary (j = jj+1, every 16th K-tile): epilogue ----
        if (((jj + 1) & (NTT - 1)) == NTT - 1) {
            if (OUT_MODE == 0) {
                bf16* Cb = (bf16*)Cout;
#pragma unroll
                for (int m = 0; m < 8; ++m) {
                    int row = m0 + wm * 128 + m * 16 + l4 * 4;
#pragma unroll
                    for (int n = 0; n < 4; ++n) {
                        int col = n0 + wn * 64 + n * 16 + l15;
#pragma unroll
                        for (int r = 0; r < 4; ++r)
                            Cb[(size_t)(row + r) * Nn + col] = (bf16)acc[m][n][r];
                    }
                }
            } else {
                float* Cf = (float*)Cout;
#pragma unroll
                for (int m = 0; m < 8; ++m) {
                    int row = m0 + wm * 128 + m * 16 + l4 * 4;
#pragma unroll
                    for (int n = 0; n < 4; ++n) {
                        int col = n0 + wn * 64 + n * 16 + l15;
                        float bv = bias[col];
#pragma unroll
                        for (int r = 0; r < 4; ++r) {
                            int lrow = (row + r) & (LL - 1);
                            float cnt = (lrow < 2 || lrow > LL - 3) ? 1.f : 2.f;
                            Cf[(size_t)(row + r) * Nn + col] = acc[m][n][r] + bv * cnt;
                        }
                    }
                }
            }
            if (jj + 2 < JT) {
#pragma unroll
                for (int m = 0; m < 8; ++m)
#pragma unroll
                    for (int n = 0; n < 4; ++n)
#pragma unroll
                        for (int r = 0; r < 4; ++r)
                            acc[m][n][r] = 0.f;
                ti += 1;
                m0 = (ti / NBN) << 8;
                n0 = (ti % NBN) << 8;
            }
        }
    }
}

// ---------------- fused windowed attention + presum: 4 waves/block ----------------
// One wave per (b, n1, h): produces the h-slice of z rows 2*n1, 2*n1+1.
// z row l = o(window n1, slot l&1) + o(window n1-1, slot (l&1)+2).
__global__ __launch_bounds__(256) void attnz_k(const bf16* __restrict__ qkv,
                                               bf16* __restrict__ z)
{
    int task = blockIdx.x * 4 + (threadIdx.x >> 6);   // (b, n1, h)
    int h = task & 7;
    int tmp = task >> 3;                              // b*1024 + n1
    int n1 = tmp & 1023;
    int b = tmp >> 10;
    int l = threadIdx.x & 63;
    const int coff = h * 128 + 2 * l;                 // this lane's 2 d-elements
    const int baserow = b * LL + 2 * n1;              // global row of q/z base
    const bool hasA = (n1 <= NW - 1);                 // window n1 exists
    const bool hasB = (n1 >= 1);                      // window n1-1 exists

    float q[2][2], k[6][2], v[6][2];
#pragma unroll
    for (int i = 0; i < 2; ++i) {
        const bf16* rp = qkv + (size_t)(baserow + i) * N3;
        u32 uq = *reinterpret_cast<const u32*>(rp + coff);
        q[i][0] = bflo(uq); q[i][1] = bfhi(uq);
    }
#pragma unroll
    for (int j = 0; j < 6; ++j) {
        int r = 2 * n1 - 2 + j;
        r = r < 0 ? 0 : (r > LL - 1 ? LL - 1 : r);    // clamp; clamped rows unused
        const bf16* rp = qkv + (size_t)(b * LL + r) * N3;
        u32 uk = *reinterpret_cast<const u32*>(rp + 1024 + coff);
        u32 uv = *reinterpret_cast<const u32*>(rp + 2048 + coff);
        k[j][0] = bflo(uk); k[j][1] = bfhi(uk);
        v[j][0] = bflo(uv); v[j][1] = bfhi(uv);
    }

    float dots[2][6];
#pragma unroll
    for (int i = 0; i < 2; ++i)
#pragma unroll
        for (int j = 0; j < 6; ++j) {
            float p = q[i][0] * k[j][0] + q[i][1] * k[j][1];
#pragma unroll
            for (int off = 32; off >= 1; off >>= 1)
                p += __shfl_xor(p, off);
            dots[i][j] = p * 0.03125f;   // * C^-0.5
        }

#pragma unroll
    for (int i = 0; i < 2; ++i) {
        float o0 = 0.f, o1 = 0.f;
        if (hasA) {    // window n1, k/v slots 2..5
            float m = fmaxf(fmaxf(dots[i][2], dots[i][3]), fmaxf(dots[i][4], dots[i][5]));
            float e[4], s = 0.f;
#pragma unroll
            for (int j = 0; j < 4; ++j) { e[j] = __expf(dots[i][2 + j] - m); s += e[j]; }
            float inv = 1.f / s;
#pragma unroll
            for (int j = 0; j < 4; ++j) {
                float a = e[j] * inv;
                o0 += a * v[2 + j][0];
                o1 += a * v[2 + j][1];
            }
        }
        if (hasB) {    // window n1-1, k/v slots 0..3
            float m = fmaxf(fmaxf(dots[i][0], dots[i][1]), fmaxf(dots[i][2], dots[i][3]));
            float e[4], s = 0.f;
#pragma unroll
            for (int j = 0; j < 4; ++j) { e[j] = __expf(dots[i][j] - m); s += e[j]; }
            float inv = 1.f / s;
#pragma unroll
            for (int j = 0; j < 4; ++j) {
                float a = e[j] * inv;
                o0 += a * v[j][0];
                o1 += a * v[j][1];
            }
        }
        u32 pk = (u32)f2bf(o0) | ((u32)f2bf(o1) << 16);
        *reinterpret_cast<u32*>(z + (size_t)(baserow + i) * CC + coff) = pk;
    }
}

// ---------------- launch ----------------
extern "C" void kernel_launch(void* const* d_in, const int* in_sizes, int n_in,
                              void* d_out, int out_size, void* d_ws, size_t ws_size,
                              hipStream_t stream)
{
    const float* x     = (const float*)d_in[0];
    const float* w_qkv = (const float*)d_in[1];
    const float* w_out = (const float*)d_in[2];
    const float* b_out = (const float*)d_in[3];
    float* out = (float*)d_out;
    char* ws = (char*)d_ws;

    // ws layout (bytes):
    bf16* xb    = (bf16*)(ws);                  // 16384*1024*2  = 33,554,432
    bf16* wqkvT = (bf16*)(ws + 33554432);       //  3072*1024*2  =  6,291,456
    bf16* woutT = (bf16*)(ws + 39845888);       //  1024*1024*2  =  2,097,152
    bf16* qkvb  = (bf16*)(ws + 41943040);       // 16384*3072*2  = 100,663,296 (ends 142,606,336)
    bf16* z     = (bf16*)(ws + 142606336);      // 16384*1024*2  = 33,554,432
    // total: 176,160,768 bytes

    cast_x_k<<<2048, 256, 0, stream>>>(x, xb, M1 * CC / 4);
    transpose_cast_k<<<dim3(N3 / 32, CC / 32), 256, 0, stream>>>(w_qkv, wqkvT, CC, N3);
    transpose_cast_k<<<dim3(CC / 32, CC / 32), 256, 0, stream>>>(w_out, woutT, CC, CC);

    // GEMM1: 16384x3072x1024 = 768 tiles -> 256 persistent blocks x 3 tiles
    gemm8p_k<0, 3, 12><<<256, 512, 0, stream>>>(xb, wqkvT, qkvb, nullptr);

    // fused attention + presum: tasks = B*1024*H = 65536, 4 waves/block
    attnz_k<<<BB * 1024 * HEADS / 4, 256, 0, stream>>>(qkvb, z);

    // GEMM2: 16384x1024x1024 = 256 tiles -> 256 blocks x 1 tile, f32 out + bias*cnt
    gemm8p_k<1, 1, 4><<<256, 512, 0, stream>>>(z, woutT, out, b_out);
}

// Round 10
// 244.584 us; speedup vs baseline: 2.0957x; 2.0957x over previous
//
#include <hip/hip_runtime.h>
#include <stdint.h>

// ---- problem constants ----
#define HEADS 8
#define KSZ   4
#define STRD  2
#define BB    8
#define LL    2048
#define CC    1024
#define N3    3072
#define NW    1023            // windows
#define M1    (BB*LL)         // 16384 rows of qkv GEMM (and of z GEMM)
#define GK    1024            // K of both GEMMs
#define NTT   16              // K-tiles per output tile (GK/64)

typedef __bf16 bf16;
typedef __bf16 bf16x8 __attribute__((ext_vector_type(8)));
typedef float  f32x4  __attribute__((ext_vector_type(4)));
typedef unsigned int  u32;
typedef unsigned short u16;

__device__ __forceinline__ float bflo(u32 u) { return __uint_as_float(u << 16); }
__device__ __forceinline__ float bfhi(u32 u) { return __uint_as_float(u & 0xffff0000u); }
__device__ __forceinline__ u16 f2bf(float f) { bf16 b = (bf16)f; return __builtin_bit_cast(u16, b); }

#define AS3(p) ((__attribute__((address_space(3))) void*)(p))
#define AS1(p) ((const __attribute__((address_space(1))) void*)(p))

// ---------------- cast x (f32 -> bf16), vectorized ----------------
__global__ __launch_bounds__(256) void cast_x_k(const float* __restrict__ in,
                                                bf16* __restrict__ out, int n4)
{
    int i = blockIdx.x * 256 + threadIdx.x;
    int stride = gridDim.x * 256;
    for (; i < n4; i += stride) {
        float4 f = reinterpret_cast<const float4*>(in)[i];
        ushort4 u;
        u.x = f2bf(f.x); u.y = f2bf(f.y); u.z = f2bf(f.z); u.w = f2bf(f.w);
        reinterpret_cast<ushort4*>(out)[i] = u;
    }
}

// ---------------- transpose + cast: src f32 [R][Ccol] -> dst bf16 [Ccol][R] ----------------
__global__ __launch_bounds__(256) void transpose_cast_k(const float* __restrict__ src,
                                                        bf16* __restrict__ dst,
                                                        int R, int Ccol)
{
    __shared__ float t[32][33];
    int tx = threadIdx.x & 31, ty = threadIdx.x >> 5;   // 32 x 8
    int c0 = blockIdx.x * 32, r0 = blockIdx.y * 32;
#pragma unroll
    for (int yy = 0; yy < 32; yy += 8)
        t[ty + yy][tx] = src[(size_t)(r0 + ty + yy) * Ccol + c0 + tx];
    __syncthreads();
#pragma unroll
    for (int yy = 0; yy < 32; yy += 8)
        dst[(size_t)(c0 + ty + yy) * R + r0 + tx] = (bf16)t[tx][ty + yy];
}

// ---------------- persistent 256x256 bf16 GEMM, 4-phase + register-neutral read-ahead ----
// Staging ledger (r5/r8-verified): stage A(j+2)@P3, B(j+2)@P4 into buf[j&1];
// vmcnt(4)@P3 (outstanding A(j+1),B(j+1),A(j+2)=12 -> drains first 8) + P3
// barrier makes buf[(j+1)&1] globally valid at P4.
// Quadrant ring: P1(aLo,bLo)->[0..3][0..1]  P2(aHi,bLo)->[4..7][0..1]
//                P3(aLo,bHi)->[0..3][2..3]  P4(aHi,bHi)->[4..7][2..3]
// Read-ahead (same 24-fragment footprint as r8): P1 issues aHi (drain@P2),
// P2 issues bHi (drain@P3), P4 tail prefetches NEXT tile's aLo,bLo from
// buf[(j+1)&1] (drain@next P1). aLo dead after P3, bLo after P2 -> WAR-clean.
__device__ __forceinline__ void stage8(const bf16* __restrict__ G, bf16* dst,
                                       int baserow, int kt,
                                       int wid, int l, int kch)
{
#pragma unroll
    for (int qd = 0; qd < 4; ++qd) {
        int row = ((wid * 4 + qd) << 3) + (l >> 3);
        const bf16* src = G + (size_t)(baserow + row) * GK + kt * 64 + kch;
        __builtin_amdgcn_global_load_lds(AS1(src), AS3(dst + (wid * 4 + qd) * 512), 16, 0, 0);
    }
}

#define LGKM0 { asm volatile("s_waitcnt lgkmcnt(0)" ::: "memory"); __builtin_amdgcn_sched_barrier(0); }
#define BARR  { __builtin_amdgcn_s_barrier(); __builtin_amdgcn_sched_barrier(0); }

template <int OUT_MODE, int T, int NBN>
__global__ __launch_bounds__(512, 1) void gemm8p_k(const bf16* __restrict__ A,
                                                   const bf16* __restrict__ Bt,
                                                   void* __restrict__ Cout,
                                                   const float* __restrict__ bias)
{
    __shared__ __attribute__((aligned(16))) bf16 sA[2][256 * 64];
    __shared__ __attribute__((aligned(16))) bf16 sB[2][256 * 64];
    const int Nn = NBN << 8;

    const int tid = threadIdx.x;
    const int l = tid & 63, wid = tid >> 6;
    const int wm = wid >> 2, wn = wid & 3;
    const int l15 = l & 15, l4 = l >> 4;
    const int xr = (l & 7) << 4;                      // read-side byte XOR (row&7 == l&7)
    const int kch = ((l & 7) ^ ((l >> 3) & 7)) * 8;   // write-side inverse-swizzled k offset

    // XCD-aware block swizzle (grid = 256, % 8 == 0, bijective)
    const int nwg = gridDim.x;
    const int wg = ((blockIdx.x & 7) * (nwg >> 3)) + (blockIdx.x >> 3);
    const int JT = T * NTT;

    int ti = wg * T;                                  // current output tile
    int m0 = (ti / NBN) << 8, n0 = (ti % NBN) << 8;

    const int rA = wm * 128 + l15;
    const int rB = wn * 64 + l15;
    int offK[2];
#pragma unroll
    for (int ks = 0; ks < 2; ++ks)
        offK[ks] = ((ks * 64 + l4 * 16) ^ xr) >> 1;

    f32x4 acc[8][4] = {};
    bf16x8 aLo[4][2], aHi[4][2], bLo[2][2], bHi[2][2];

    // prologue: K-tile 0 -> buf0, K-tile 1 -> buf1 (tile ti)
    stage8(A, sA[0], m0, 0, wid, l, kch);
    stage8(Bt, sB[0], n0, 0, wid, l, kch);
    stage8(A, sA[1], m0, 1, wid, l, kch);
    stage8(Bt, sB[1], n0, 1, wid, l, kch);
    asm volatile("s_waitcnt vmcnt(8)" ::: "memory");   // K-tile 0 landed (own)
    __builtin_amdgcn_s_barrier();                      // -> all waves' tile-0 landed
    __builtin_amdgcn_sched_barrier(0);
    // pre-read tile-0 aLo,bLo (drained at first P1 LGKM0)
#pragma unroll
    for (int m = 0; m < 4; ++m)
#pragma unroll
        for (int ks = 0; ks < 2; ++ks)
            aLo[m][ks] = *(const bf16x8*)(&sA[0][(rA + m * 16) * 64 + offK[ks]]);
#pragma unroll
    for (int n = 0; n < 2; ++n)
#pragma unroll
        for (int ks = 0; ks < 2; ++ks)
            bLo[n][ks] = *(const bf16x8*)(&sB[0][(rB + n * 16) * 64 + offK[ks]]);

    for (int j = 0; j < JT; ++j) {
        const bf16* tA = sA[j & 1];
        const bf16* tB = sB[j & 1];
        bf16* wA = sA[j & 1];
        bf16* wB = sB[j & 1];
        const bf16* nA = sA[(j + 1) & 1];
        const bf16* nB = sB[(j + 1) & 1];

        // next-stage coordinates (tile of j+2)
        const int jn = j + 2;
        const bool doStage = jn < JT;
        int ktn = jn & (NTT - 1), m0n = 0, n0n = 0;
        if (doStage) {
            int tin = wg * T + (jn >> 4);              // NTT == 16
            m0n = (tin / NBN) << 8;
            n0n = (tin % NBN) << 8;
        }

        // ---- P1: drain prefetched aLo,bLo; issue aHi; MFMA (aLo,bLo) -> [0..3][0..1] ----
        LGKM0
#pragma unroll
        for (int m = 0; m < 4; ++m)
#pragma unroll
            for (int ks = 0; ks < 2; ++ks)
                aHi[m][ks] = *(const bf16x8*)(&tA[(rA + 64 + m * 16) * 64 + offK[ks]]);
        __builtin_amdgcn_s_setprio(1);
#pragma unroll
        for (int m = 0; m < 4; ++m)
#pragma unroll
            for (int n = 0; n < 2; ++n)
#pragma unroll
                for (int ks = 0; ks < 2; ++ks)
                    acc[m][n] = __builtin_amdgcn_mfma_f32_16x16x32_bf16(aLo[m][ks], bLo[n][ks], acc[m][n], 0, 0, 0);
        __builtin_amdgcn_s_setprio(0);
        BARR

        // ---- P2: drain aHi; issue bHi; MFMA (aHi,bLo) -> [4..7][0..1] ----
        // (after this barrier all A-reads of tile j are drained -> P3 stage safe)
        LGKM0
#pragma unroll
        for (int n = 0; n < 2; ++n)
#pragma unroll
            for (int ks = 0; ks < 2; ++ks)
                bHi[n][ks] = *(const bf16x8*)(&tB[(rB + 32 + n * 16) * 64 + offK[ks]]);
        __builtin_amdgcn_s_setprio(1);
#pragma unroll
        for (int m = 0; m < 4; ++m)
#pragma unroll
            for (int n = 0; n < 2; ++n)
#pragma unroll
                for (int ks = 0; ks < 2; ++ks)
                    acc[4 + m][n] = __builtin_amdgcn_mfma_f32_16x16x32_bf16(aHi[m][ks], bLo[n][ks], acc[4 + m][n], 0, 0, 0);
        __builtin_amdgcn_s_setprio(0);
        BARR

        // ---- P3: drain bHi; stage A(j+2); MFMA (aLo,bHi) -> [0..3][2..3]; vmcnt; barrier ----
        // (vmcnt(4): A(j+1),B(j+1) landed -> after barrier buf[(j+1)&1] valid)
        LGKM0
        if (doStage)
            stage8(A, wA, m0n, ktn, wid, l, kch);
        __builtin_amdgcn_s_setprio(1);
#pragma unroll
        for (int m = 0; m < 4; ++m)
#pragma unroll
            for (int n = 0; n < 2; ++n)
#pragma unroll
                for (int ks = 0; ks < 2; ++ks)
                    acc[m][2 + n] = __builtin_amdgcn_mfma_f32_16x16x32_bf16(aLo[m][ks], bHi[n][ks], acc[m][2 + n], 0, 0, 0);
        __builtin_amdgcn_s_setprio(0);
        if (j < JT - 2)
            asm volatile("s_waitcnt vmcnt(4)" ::: "memory");
        else if (j == JT - 2)
            asm volatile("s_waitcnt vmcnt(0)" ::: "memory");
        BARR

        // ---- P4: stage B(j+2); MFMA (aHi,bHi) -> [4..7][2..3]; prefetch next aLo,bLo ----
        if (doStage)
            stage8(Bt, wB, n0n, ktn, wid, l, kch);
        __builtin_amdgcn_s_setprio(1);
#pragma unroll
        for (int m = 0; m < 4; ++m)
#pragma unroll
            for (int n = 0; n < 2; ++n)
#pragma unroll
                for (int ks = 0; ks < 2; ++ks)
                    acc[4 + m][2 + n] = __builtin_amdgcn_mfma_f32_16x16x32_bf16(aHi[m][ks], bHi[n][ks], acc[4 + m][2 + n], 0, 0, 0);
        __builtin_amdgcn_s_setprio(0);
        if (j + 1 < JT) {
#pragma unroll
            for (int m = 0; m < 4; ++m)
#pragma unroll
                for (int ks = 0; ks < 2; ++ks)
                    aLo[m][ks] = *(const bf16x8*)(&nA[(rA + m * 16) * 64 + offK[ks]]);
#pragma unroll
            for (int n = 0; n < 2; ++n)
#pragma unroll
                for (int ks = 0; ks < 2; ++ks)
                    bLo[n][ks] = *(const bf16x8*)(&nB[(rB + n * 16) * 64 + offK[ks]]);
        }
        BARR

        // ---- output-tile boundary: epilogue (no LDS access), then reset ----
        if ((j & (NTT - 1)) == NTT - 1) {
            if (OUT_MODE == 0) {
                bf16* Cb = (bf16*)Cout;
#pragma unroll
                for (int m = 0; m < 8; ++m) {
                    int row = m0 + wm * 128 + m * 16 + l4 * 4;
#pragma unroll
                    for (int n = 0; n < 4; ++n) {
                        int col = n0 + wn * 64 + n * 16 + l15;
#pragma unroll
                        for (int r = 0; r < 4; ++r)
                            Cb[(size_t)(row + r) * Nn + col] = (bf16)acc[m][n][r];
                    }
                }
            } else {
                float* Cf = (float*)Cout;
#pragma unroll
                for (int m = 0; m < 8; ++m) {
                    int row = m0 + wm * 128 + m * 16 + l4 * 4;
#pragma unroll
                    for (int n = 0; n < 4; ++n) {
                        int col = n0 + wn * 64 + n * 16 + l15;
                        float bv = bias[col];
#pragma unroll
                        for (int r = 0; r < 4; ++r) {
                            int lrow = (row + r) & (LL - 1);
                            float cnt = (lrow < 2 || lrow > LL - 3) ? 1.f : 2.f;
                            Cf[(size_t)(row + r) * Nn + col] = acc[m][n][r] + bv * cnt;
                        }
                    }
                }
            }
            if (j + 1 < JT) {
#pragma unroll
                for (int m = 0; m < 8; ++m)
#pragma unroll
                    for (int n = 0; n < 4; ++n)
#pragma unroll
                        for (int r = 0; r < 4; ++r)
                            acc[m][n][r] = 0.f;
                ti += 1;
                m0 = (ti / NBN) << 8;
                n0 = (ti % NBN) << 8;
            }
        }
    }
}

// ---------------- fused windowed attention + presum: 4 waves/block ----------------
// One wave per (b, n1, h): produces the h-slice of z rows 2*n1, 2*n1+1.
// z row l = o(window n1, slot l&1) + o(window n1-1, slot (l&1)+2).
__global__ __launch_bounds__(256) void attnz_k(const bf16* __restrict__ qkv,
                                               bf16* __restrict__ z)
{
    int task = blockIdx.x * 4 + (threadIdx.x >> 6);   // (b, n1, h)
    int h = task & 7;
    int tmp = task >> 3;                              // b*1024 + n1
    int n1 = tmp & 1023;
    int b = tmp >> 10;
    int l = threadIdx.x & 63;
    const int coff = h * 128 + 2 * l;                 // this lane's 2 d-elements
    const int baserow = b * LL + 2 * n1;              // global row of q/z base
    const bool hasA = (n1 <= NW - 1);                 // window n1 exists
    const bool hasB = (n1 >= 1);                      // window n1-1 exists

    float q[2][2], k[6][2], v[6][2];
#pragma unroll
    for (int i = 0; i < 2; ++i) {
        const bf16* rp = qkv + (size_t)(baserow + i) * N3;
        u32 uq = *reinterpret_cast<const u32*>(rp + coff);
        q[i][0] = bflo(uq); q[i][1] = bfhi(uq);
    }
#pragma unroll
    for (int j = 0; j < 6; ++j) {
        int r = 2 * n1 - 2 + j;
        r = r < 0 ? 0 : (r > LL - 1 ? LL - 1 : r);    // clamp; clamped rows unused
        const bf16* rp = qkv + (size_t)(b * LL + r) * N3;
        u32 uk = *reinterpret_cast<const u32*>(rp + 1024 + coff);
        u32 uv = *reinterpret_cast<const u32*>(rp + 2048 + coff);
        k[j][0] = bflo(uk); k[j][1] = bfhi(uk);
        v[j][0] = bflo(uv); v[j][1] = bfhi(uv);
    }

    float dots[2][6];
#pragma unroll
    for (int i = 0; i < 2; ++i)
#pragma unroll
        for (int j = 0; j < 6; ++j) {
            float p = q[i][0] * k[j][0] + q[i][1] * k[j][1];
#pragma unroll
            for (int off = 32; off >= 1; off >>= 1)
                p += __shfl_xor(p, off);
            dots[i][j] = p * 0.03125f;   // * C^-0.5
        }

#pragma unroll
    for (int i = 0; i < 2; ++i) {
        float o0 = 0.f, o1 = 0.f;
        if (hasA) {    // window n1, k/v slots 2..5
            float m = fmaxf(fmaxf(dots[i][2], dots[i][3]), fmaxf(dots[i][4], dots[i][5]));
            float e[4], s = 0.f;
#pragma unroll
            for (int j = 0; j < 4; ++j) { e[j] = __expf(dots[i][2 + j] - m); s += e[j]; }
            float inv = 1.f / s;
#pragma unroll
            for (int j = 0; j < 4; ++j) {
                float a = e[j] * inv;
                o0 += a * v[2 + j][0];
                o1 += a * v[2 + j][1];
            }
        }
        if (hasB) {    // window n1-1, k/v slots 0..3
            float m = fmaxf(fmaxf(dots[i][0], dots[i][1]), fmaxf(dots[i][2], dots[i][3]));
            float e[4], s = 0.f;
#pragma unroll
            for (int j = 0; j < 4; ++j) { e[j] = __expf(dots[i][j] - m); s += e[j]; }
            float inv = 1.f / s;
#pragma unroll
            for (int j = 0; j < 4; ++j) {
                float a = e[j] * inv;
                o0 += a * v[j][0];
                o1 += a * v[j][1];
            }
        }
        u32 pk = (u32)f2bf(o0) | ((u32)f2bf(o1) << 16);
        *reinterpret_cast<u32*>(z + (size_t)(baserow + i) * CC + coff) = pk;
    }
}

// ---------------- launch ----------------
extern "C" void kernel_launch(void* const* d_in, const int* in_sizes, int n_in,
                              void* d_out, int out_size, void* d_ws, size_t ws_size,
                              hipStream_t stream)
{
    const float* x     = (const float*)d_in[0];
    const float* w_qkv = (const float*)d_in[1];
    const float* w_out = (const float*)d_in[2];
    const float* b_out = (const float*)d_in[3];
    float* out = (float*)d_out;
    char* ws = (char*)d_ws;

    // ws layout (bytes):
    bf16* xb    = (bf16*)(ws);                  // 16384*1024*2  = 33,554,432
    bf16* wqkvT = (bf16*)(ws + 33554432);       //  3072*1024*2  =  6,291,456
    bf16* woutT = (bf16*)(ws + 39845888);       //  1024*1024*2  =  2,097,152
    bf16* qkvb  = (bf16*)(ws + 41943040);       // 16384*3072*2  = 100,663,296 (ends 142,606,336)
    bf16* z     = (bf16*)(ws + 142606336);      // 16384*1024*2  = 33,554,432
    // total: 176,160,768 bytes

    cast_x_k<<<2048, 256, 0, stream>>>(x, xb, M1 * CC / 4);
    transpose_cast_k<<<dim3(N3 / 32, CC / 32), 256, 0, stream>>>(w_qkv, wqkvT, CC, N3);
    transpose_cast_k<<<dim3(CC / 32, CC / 32), 256, 0, stream>>>(w_out, woutT, CC, CC);

    // GEMM1: 16384x3072x1024 = 768 tiles -> 256 persistent blocks x 3 tiles
    gemm8p_k<0, 3, 12><<<256, 512, 0, stream>>>(xb, wqkvT, qkvb, nullptr);

    // fused attention + presum: tasks = B*1024*H = 65536, 4 waves/block
    attnz_k<<<BB * 1024 * HEADS / 4, 256, 0, stream>>>(qkvb, z);

    // GEMM2: 16384x1024x1024 = 256 tiles -> 256 blocks x 1 tile, f32 out + bias*cnt
    gemm8p_k<1, 1, 4><<<256, 512, 0, stream>>>(z, woutT, out, b_out);
}